// Round 13
// baseline (301.258 us; speedup 1.0000x reference)
//
#include <hip/hip_runtime.h>
#include <cstdint>

#define SEQ 4096
#define NH 12
#define DH 64
#define DM 768
#define MT 8192      // B*SEQ
#define QKVN 2304    // 3*DM

typedef __bf16 bf16;
typedef __attribute__((ext_vector_type(8))) __bf16 bf16x8;
typedef __attribute__((ext_vector_type(4))) __bf16 bf16x4;
typedef __attribute__((ext_vector_type(2))) __bf16 bf16x2;
typedef __attribute__((ext_vector_type(4))) float f32x4;
typedef __attribute__((ext_vector_type(16))) float f32x16;
typedef __attribute__((ext_vector_type(2))) int int2v;

// async global->LDS, 16B per lane. LDS dest is wave-uniform base + lane*16.
__device__ __forceinline__ void async_ld16(const void* g, void* lds) {
  __builtin_amdgcn_global_load_lds(
      (__attribute__((address_space(1))) void*)(void*)g,
      (__attribute__((address_space(3))) void*)lds, 16, 0, 0);
}

// pack two f32 -> bf16x2 bits (RTZ via shift is avoided; use cvt builtin if present)
__device__ __forceinline__ int pk_bf16(float a, float b) {
#if __has_builtin(__builtin_amdgcn_cvt_pk_bf16_f32)
  union { bf16x2 v; int i; } u;
  u.v = __builtin_amdgcn_cvt_pk_bf16_f32(a, b);
  return u.i;
#else
  union { int i; bf16 h[2]; } u;
  u.h[0] = (bf16)a; u.h[1] = (bf16)b;
  return u.i;
#endif
}

// Schraudolph-style exp2 emitting BF16 BITS directly, two elements packed.
__device__ __forceinline__ int pexp2_pair(float s0, float s1) {
  int j0 = (int)__builtin_fmaf(s0, 128.0f, 16251.5f);
  int j1 = (int)__builtin_fmaf(s1, 128.0f, 16251.5f);
  return j0 | (j1 << 16);
}

// (a,b) -> a' = {a.lo32, b.lo32}, b' = {a.hi32, b.hi32}
__device__ __forceinline__ void lane32_swap(int& a, int& b) {
#if __has_builtin(__builtin_amdgcn_permlane32_swap)
  int2v r = __builtin_amdgcn_permlane32_swap(a, b, false, false);
  a = r.x; b = r.y;
#else
  int hi = (threadIdx.x & 63) >> 5;
  int ra = __shfl_xor(a, 32, 64), rb = __shfl_xor(b, 32, 64);
  int na = hi ? rb : a;
  int nb = hi ? b : ra;
  a = na; b = nb;
#endif
}

// ---------------------------------------------------------------- convert (qkv_w only)
__global__ void cvt_w(const float* __restrict__ in, bf16* __restrict__ out, int n4) {
  int i = blockIdx.x * blockDim.x + threadIdx.x;
  if (i >= n4) return;
  f32x4 v = ((const f32x4*)in)[i];
  bf16x4 o;
  o.x = (bf16)v.x; o.y = (bf16)v.y; o.z = (bf16)v.z; o.w = (bf16)v.w;
  ((bf16x4*)out)[i] = o;
}

// ---------------------------------------------------------------- GEMM (B^T)
// C[M,N] = A[M,K] @ Bw[N,K]^T. 128x128 tile, BK=32, 4 waves, 64x64/wave.
// 1-D grid, grouped swizzle (R10-verified). fp32 operands are staged DIRECTLY
// (no pre-convert pass): f32 tiles use 16 chunks of 8 rows x 32 f32, granule
// XOR-swizzled on the global side (g = (lane&7)^(row&7)) so fragment b128 reads
// land 2-way-per-bank (free). Fragments convert f32->bf16 via cvt_pk at load.
// MODE 0: A = x (fp32), B = qkv_w (bf16). Epilogue: Q(*0.125*log2e)/K scatter,
//         V^T via LDS bounce.
// MODE 1: A = attnV (bf16), B = out_w (fp32). Epilogue: +bias fp32 [M,N].
template<int MODE>
__global__ __launch_bounds__(256) void gemm_bt(
    const void* __restrict__ Av, const void* __restrict__ Bv,
    const float* __restrict__ bias,
    bf16* __restrict__ outQ, bf16* __restrict__ outK, bf16* __restrict__ outVt,
    float* __restrict__ outF,
    int M, int N, int K)
{
  __shared__ float sAf[MODE == 0 ? 128 * 32 : 1];
  __shared__ bf16  sAh[MODE == 0 ? 1 : 128 * 32];
  __shared__ bf16  sBh[MODE == 0 ? 128 * 32 : 1];
  __shared__ float sBf[MODE == 0 ? 1 : 128 * 32];
  __shared__ bf16  sT[MODE == 0 ? 64 * 136 : 1];   // V^T bounce buffer

  const int tid  = threadIdx.x;
  const int wave = tid >> 6;
  const int lane = tid & 63;
  const int l15  = lane & 15;
  const int quad = lane >> 4;

  constexpr int NT = (MODE == 0) ? (QKVN / 128) : (DM / 128);
  const int lin = blockIdx.x;
  const int rem = lin % (NT * 8);
  const int m0 = ((lin / (NT * 8)) * 8 + (rem % 8)) * 128;
  const int n0 = (rem / 8) * 128;

  const int rowbase = (wave >> 1) * 64;
  const int colbase = (wave & 1) * 64;

  f32x4 acc[4][4] = {};

  const int sr  = lane >> 2;          // bf16 chunk: row within 16-row chunk
  const int sc  = (lane & 3) * 8;     // bf16 chunk: col (8 bf16 = 16B)
  const int fr  = lane >> 3;          // f32 chunk: row within 8-row chunk
  const int fg  = (lane & 7) ^ (lane >> 3);  // f32 chunk: logical granule (swizzled)
  const int k8  = l15 & 7;            // frag row & 7 (rowbase/rt*16 are mult of 8)

  const float* Afp = (const float*)Av;
  const bf16*  Ahp = (const bf16*)Av;
  const bf16*  Bhp = (const bf16*)Bv;
  const float* Bfp = (const float*)Bv;

  for (int kt = 0; kt < K; kt += 32) {
    // 24 chunks of 1KB: MODE0 = 16 f32-A + 8 bf16-B; MODE1 = 8 bf16-A + 16 f32-B
#pragma unroll
    for (int p = 0; p < 6; ++p) {
      int chunk = p * 4 + wave;
      if (MODE == 0) {
        if (chunk < 16) {
          int row = chunk * 8 + fr;
          async_ld16(Afp + (size_t)(m0 + row) * K + kt + fg * 4, &sAf[chunk * 256]);
        } else {
          int bc = chunk - 16;
          int r = bc * 16 + sr;
          async_ld16(Bhp + (size_t)(n0 + r) * K + kt + sc, &sBh[bc * 512]);
        }
      } else {
        if (chunk < 8) {
          int r = chunk * 16 + sr;
          async_ld16(Ahp + (size_t)(m0 + r) * K + kt + sc, &sAh[chunk * 512]);
        } else {
          int bc = chunk - 8;
          int row = bc * 8 + fr;
          async_ld16(Bfp + (size_t)(n0 + row) * K + kt + fg * 4, &sBf[bc * 256]);
        }
      }
    }
    __syncthreads();

    bf16x8 af[4], bfr[4];
#pragma unroll
    for (int rt = 0; rt < 4; ++rt) {
      int r = rowbase + rt * 16 + l15;
      if (MODE == 0) {
        int pg0 = (quad * 2) ^ k8, pg1 = (quad * 2 + 1) ^ k8;
        f32x4 a0 = *(const f32x4*)&sAf[r * 32 + pg0 * 4];
        f32x4 a1 = *(const f32x4*)&sAf[r * 32 + pg1 * 4];
        union { int i[4]; bf16x8 v; } u;
        u.i[0] = pk_bf16(a0.x, a0.y); u.i[1] = pk_bf16(a0.z, a0.w);
        u.i[2] = pk_bf16(a1.x, a1.y); u.i[3] = pk_bf16(a1.z, a1.w);
        af[rt] = u.v;
      } else {
        af[rt] = *(const bf16x8*)&sAh[r * 32 + quad * 8];
      }
    }
#pragma unroll
    for (int ct = 0; ct < 4; ++ct) {
      int r = colbase + ct * 16 + l15;
      if (MODE == 0) {
        bfr[ct] = *(const bf16x8*)&sBh[r * 32 + quad * 8];
      } else {
        int pg0 = (quad * 2) ^ k8, pg1 = (quad * 2 + 1) ^ k8;
        f32x4 b0 = *(const f32x4*)&sBf[r * 32 + pg0 * 4];
        f32x4 b1 = *(const f32x4*)&sBf[r * 32 + pg1 * 4];
        union { int i[4]; bf16x8 v; } u;
        u.i[0] = pk_bf16(b0.x, b0.y); u.i[1] = pk_bf16(b0.z, b0.w);
        u.i[2] = pk_bf16(b1.x, b1.y); u.i[3] = pk_bf16(b1.z, b1.w);
        bfr[ct] = u.v;
      }
    }
#pragma unroll
    for (int rt = 0; rt < 4; ++rt)
#pragma unroll
      for (int ct = 0; ct < 4; ++ct)
        acc[rt][ct] = __builtin_amdgcn_mfma_f32_16x16x32_bf16(af[rt], bfr[ct], acc[rt][ct], 0, 0, 0);
    __syncthreads();
  }

  if (MODE == 0) {
    const int g = n0 / DM;                       // uniform per block (0=q,1=k,2=v)
    if (g < 2) {
      const float qscale = 0.125f * 1.4426950408889634f;  // fold /8 and log2(e)
#pragma unroll
      for (int ct = 0; ct < 4; ++ct) {
        int j = n0 + colbase + ct * 16 + l15;
        float bj = bias[j];
        int f = j % DM;
        int h = f >> 6, d = f & 63;
#pragma unroll
        for (int rt = 0; rt < 4; ++rt) {
          int mrow = m0 + rowbase + rt * 16 + quad * 4;
#pragma unroll
          for (int r = 0; r < 4; ++r) {
            float v = acc[rt][ct][r] + bj;
            int m = mrow + r;
            int b = m >> 12, n = m & 4095;
            int bh = b * NH + h;
            if (g == 0) outQ[((size_t)bh * SEQ + n) * DH + d] = (bf16)(v * qscale);
            else        outK[((size_t)bh * SEQ + n) * DH + d] = (bf16)v;
          }
        }
      }
    } else {
      // V block: bounce through LDS, store V^T coalesced along n
      const int f0 = n0 - 2 * DM;
      const int b = m0 >> 12, n0m = m0 & 4095;
#pragma unroll
      for (int p = 0; p < 2; ++p) {
        __syncthreads();
        if (colbase == p * 64) {
#pragma unroll
          for (int ct = 0; ct < 4; ++ct) {
            int jl = ct * 16 + l15;
            float bj = bias[n0 + p * 64 + jl];
#pragma unroll
            for (int rt = 0; rt < 4; ++rt) {
              int ml = rowbase + rt * 16 + quad * 4;
#pragma unroll
              for (int r = 0; r < 4; ++r)
                sT[jl * 136 + ml + r] = (bf16)(acc[rt][ct][r] + bj);
            }
          }
        }
        __syncthreads();
#pragma unroll
        for (int p2 = 0; p2 < 4; ++p2) {
          int slot = p2 * 256 + tid;
          int jr = slot >> 4, mc = (slot & 15) * 8;
          int fj = f0 + p * 64 + jr;
          int h = fj >> 6, d = fj & 63;
          *(bf16x8*)&outVt[((size_t)(b * NH + h) * DH + d) * SEQ + n0m + mc] =
              *(const bf16x8*)&sT[jr * 136 + mc];
        }
      }
    }
  } else {
#pragma unroll
    for (int ct = 0; ct < 4; ++ct) {
      int j = n0 + colbase + ct * 16 + l15;
      float bj = bias[j];
#pragma unroll
      for (int rt = 0; rt < 4; ++rt) {
        int mrow = m0 + rowbase + rt * 16 + quad * 4;
#pragma unroll
        for (int r = 0; r < 4; ++r)
          outF[(size_t)(mrow + r) * N + j] = acc[rt][ct][r] + bj;
      }
    }
  }
}

// ---------------------------------------------------------------- flash attention v12
// R9/R12 flash VERBATIM (proven 125-130 us: VGPR 84, occ ~28%, MfmaUtil ~46%).
// Register-cliff note: any second live s-vector (R10/R11) drops occ to ~17.5%.
__global__ __launch_bounds__(256) void flash_attn(
    const bf16* __restrict__ Q, const bf16* __restrict__ Kg,
    const bf16* __restrict__ Vt, bf16* __restrict__ Oout)
{
  __shared__ bf16 sK[2][64 * 64];    // [key][d], granule-swizzled
  __shared__ bf16 sV[2][64 * 64];    // [d][key], granule-swizzled

  const int tid  = threadIdx.x;
  const int wave = tid >> 6;
  const int lane = tid & 63;
  const int l31  = lane & 31;
  const int hi   = lane >> 5;
  const int bh = blockIdx.y;
  const int q0w = blockIdx.x * 128 + wave * 32;

  const bf16* Qb = Q  + (size_t)bh * SEQ * DH;
  const bf16* Kb = Kg + (size_t)bh * SEQ * DH;
  const bf16* Vb = Vt + (size_t)bh * DH * SEQ;

  const int srow = lane >> 3;
  const int spg  = lane & 7;

  bf16x8 qf[4];
#pragma unroll
  for (int dc = 0; dc < 4; ++dc)
    qf[dc] = *(const bf16x8*)&Qb[(size_t)(q0w + l31) * DH + dc * 16 + hi * 8];

  bf16x8 ones1;
#pragma unroll
  for (int j = 0; j < 8; ++j) ones1[j] = (bf16)1.0f;

  f32x16 o0 = {}, o1 = {}, o2 = {};
  f32x16 zc = {};

  const int keyk = (l31 & 7) ^ (((l31 >> 3) & 3) << 1);
  int kOff[4], vOff[4];
#pragma unroll
  for (int dc = 0; dc < 4; ++dc)
    kOff[dc] = l31 * 64 + (((dc * 2 + hi) ^ keyk) * 8);
#pragma unroll
  for (int k4 = 0; k4 < 4; ++k4)
    vOff[k4] = l31 * 64 + (((k4 * 2 + hi) ^ keyk) * 8);

  auto stage = [&](int kt, int buf) {
#pragma unroll
    for (int j = 0; j < 2; ++j) {
      int r0 = wave * 16 + j * 8;
      int row = r0 + srow;
      int lg = spg ^ (row & 7) ^ (((row >> 3) & 3) << 1);
      async_ld16(Kb + (size_t)(kt + row) * DH + lg * 8, &sK[buf][r0 * 64]);
      async_ld16(Vb + (size_t)row * SEQ + kt + lg * 8, &sV[buf][r0 * 64]);
    }
  };

  auto compute = [&](const bf16* sKp, const bf16* sVp) {
#pragma unroll
    for (int kb = 0; kb < 2; ++kb) {
      f32x16 s;
      {
        bf16x8 kf = *(const bf16x8*)&sKp[kOff[0] + kb * 2048];
        s = __builtin_amdgcn_mfma_f32_32x32x16_bf16(kf, qf[0], zc, 0, 0, 0);
      }
#pragma unroll
      for (int dc = 1; dc < 4; ++dc) {
        bf16x8 kf = *(const bf16x8*)&sKp[kOff[dc] + kb * 2048];
        s = __builtin_amdgcn_mfma_f32_32x32x16_bf16(kf, qf[dc], s, 0, 0, 0);
      }
#pragma unroll
      for (int kc = 0; kc < 2; ++kc) {
        int g0a = pexp2_pair(s[8 * kc + 0], s[8 * kc + 1]);
        int g0b = pexp2_pair(s[8 * kc + 2], s[8 * kc + 3]);
        int g1a = pexp2_pair(s[8 * kc + 4], s[8 * kc + 5]);
        int g1b = pexp2_pair(s[8 * kc + 6], s[8 * kc + 7]);
        lane32_swap(g0a, g1a);
        lane32_swap(g0b, g1b);
        union { int i[4]; bf16x8 v; } Af;
        Af.i[0] = g0a; Af.i[1] = g0b; Af.i[2] = g1a; Af.i[3] = g1b;
        bf16x8 vf0 = *(const bf16x8*)&sVp[vOff[kb * 2 + kc]];
        bf16x8 vf1 = *(const bf16x8*)&sVp[vOff[kb * 2 + kc] + 2048];
        o0 = __builtin_amdgcn_mfma_f32_32x32x16_bf16(Af.v, vf0, o0, 0, 0, 0);
        o1 = __builtin_amdgcn_mfma_f32_32x32x16_bf16(Af.v, vf1, o1, 0, 0, 0);
        o2 = __builtin_amdgcn_mfma_f32_32x32x16_bf16(Af.v, ones1, o2, 0, 0, 0);
      }
    }
  };

  stage(0, 0);
  __syncthreads();

  for (int kt = 0; kt < SEQ; kt += 128) {
    if (kt + 64 < SEQ) stage(kt + 64, 1);
    compute(sK[0], sV[0]);
    __syncthreads();
    if (kt + 128 < SEQ) stage(kt + 128, 0);
    compute(sK[1], sV[1]);
    __syncthreads();
  }

  const int bg = bh / NH, h = bh % NH;
#pragma unroll
  for (int i = 0; i < 16; ++i) {
    int ql = 8 * (i >> 2) + (i & 3) + 4 * hi;
    float inv = 1.0f / o2[i];
    size_t base = (size_t)(bg * SEQ + q0w + ql) * DM + h * DH;
    Oout[base + l31]      = (bf16)(o0[i] * inv);
    Oout[base + 32 + l31] = (bf16)(o1[i] * inv);
  }
}

// ---------------------------------------------------------------- launcher
extern "C" void kernel_launch(void* const* d_in, const int* in_sizes, int n_in,
                              void* d_out, int out_size, void* d_ws, size_t ws_size,
                              hipStream_t stream) {
  const float* x     = (const float*)d_in[0];
  const float* qkv_w = (const float*)d_in[1];
  const float* qkv_b = (const float*)d_in[2];
  const float* out_w = (const float*)d_in[3];
  const float* out_b = (const float*)d_in[4];
  float* out = (float*)d_out;

  char* w = (char*)d_ws;
  bf16* wqkv  = (bf16*)w; w += (size_t)QKVN * DM * 2;      // bf16 qkv weights
  bf16* Qw    = (bf16*)w; w += (size_t)MT * DM * 2;        // [bh][n][d], scaled 0.125*log2e
  bf16* Kw    = (bf16*)w; w += (size_t)MT * DM * 2;        // [bh][n][d]
  bf16* Vtw   = (bf16*)w; w += (size_t)MT * DM * 2;        // [bh][d][n]
  bf16* attnV = (bf16*)w; w += (size_t)MT * DM * 2;        // [m][768]

  const int nw4 = QKVN * DM / 4;
  cvt_w<<<dim3((nw4 + 255) / 256), 256, 0, stream>>>(qkv_w, wqkv, nw4);

  gemm_bt<0><<<dim3((QKVN / 128) * (MT / 128)), 256, 0, stream>>>(
      x, wqkv, qkv_b, Qw, Kw, Vtw, nullptr, MT, QKVN, DM);

  flash_attn<<<dim3(SEQ / 128, 2 * NH), 256, 0, stream>>>(Qw, Kw, Vtw, attnV);

  gemm_bt<1><<<dim3((DM / 128) * (MT / 128)), 256, 0, stream>>>(
      attnV, out_w, out_b, nullptr, nullptr, nullptr, out, MT, DM, DM);
}

// Round 14
// 281.544 us; speedup vs baseline: 1.0700x; 1.0700x over previous
//
#include <hip/hip_runtime.h>
#include <cstdint>

#define SEQ 4096
#define NH 12
#define DH 64
#define DM 768
#define MT 8192      // B*SEQ
#define QKVN 2304    // 3*DM

typedef __bf16 bf16;
typedef __attribute__((ext_vector_type(8))) __bf16 bf16x8;
typedef __attribute__((ext_vector_type(4))) __bf16 bf16x4;
typedef __attribute__((ext_vector_type(2))) __bf16 bf16x2;
typedef __attribute__((ext_vector_type(4))) float f32x4;
typedef __attribute__((ext_vector_type(16))) float f32x16;
typedef __attribute__((ext_vector_type(2))) int int2v;

// async global->LDS, 16B per lane. LDS dest is wave-uniform base + lane*16.
__device__ __forceinline__ void async_ld16(const void* g, void* lds) {
  __builtin_amdgcn_global_load_lds(
      (__attribute__((address_space(1))) void*)(void*)g,
      (__attribute__((address_space(3))) void*)lds, 16, 0, 0);
}

// Schraudolph-style exp2 emitting BF16 BITS directly, two elements packed.
// bf16(2^s) bits ~= (int)(s*128 + 16251.5); +-3.5% rel, softmax-ratio cancels
// the common mode. Integer/VALU only — never touches the trans pipe.
__device__ __forceinline__ int pexp2_pair(float s0, float s1) {
  int j0 = (int)__builtin_fmaf(s0, 128.0f, 16251.5f);
  int j1 = (int)__builtin_fmaf(s1, 128.0f, 16251.5f);
  return j0 | (j1 << 16);
}

// (a,b) -> a' = {a.lo32, b.lo32}, b' = {a.hi32, b.hi32}
__device__ __forceinline__ void lane32_swap(int& a, int& b) {
#if __has_builtin(__builtin_amdgcn_permlane32_swap)
  int2v r = __builtin_amdgcn_permlane32_swap(a, b, false, false);
  a = r.x; b = r.y;
#else
  int hi = (threadIdx.x & 63) >> 5;
  int ra = __shfl_xor(a, 32, 64), rb = __shfl_xor(b, 32, 64);
  int na = hi ? rb : a;
  int nb = hi ? b : ra;
  a = na; b = nb;
#endif
}

// ---------------------------------------------------------------- converts (merged)
#define NX4  (MT * DM / 4)
#define NW14 (QKVN * DM / 4)
#define NW24 (DM * DM / 4)
__global__ void cvt_all(const float* __restrict__ x, const float* __restrict__ w1,
                        const float* __restrict__ w2, bf16* __restrict__ xb,
                        bf16* __restrict__ wb1, bf16* __restrict__ wb2) {
  int i = blockIdx.x * blockDim.x + threadIdx.x;
  const float* src; bf16* dst; int j;
  if (i < NX4) { src = x; dst = xb; j = i; }
  else if (i < NX4 + NW14) { src = w1; dst = wb1; j = i - NX4; }
  else if (i < NX4 + NW14 + NW24) { src = w2; dst = wb2; j = i - NX4 - NW14; }
  else return;
  f32x4 v = ((const f32x4*)src)[j];
  bf16x4 o;
  o.x = (bf16)v.x; o.y = (bf16)v.y; o.z = (bf16)v.z; o.w = (bf16)v.w;
  ((bf16x4*)dst)[j] = o;
}

// ---------------------------------------------------------------- GEMM (B^T)
// C[M,N] = A[M,K] @ Bw[N,K]^T. 128x128 tile, BK=32, 4 waves, 64x64/wave.
// 1-D grid with grouped swizzle (R10-verified: non-flash 162 -> 146.5 us).
// R13 errata: staging fp32 operands directly (to skip the convert pass) regressed
// ~23 us — doubled A staging bytes/DMA count and cut blocks/CU 4->3. Keep bf16.
// MODE 0: QKV epilogue -> +bias, Q(*0.125*log2e)/K as [bh][n][d]; V^T via LDS -> [bh][d][n]
// MODE 1: out-proj epilogue -> +bias, fp32 row-major [M,N]
template<int MODE>
__global__ __launch_bounds__(256) void gemm_bt(
    const bf16* __restrict__ A, const bf16* __restrict__ Bw,
    const float* __restrict__ bias,
    bf16* __restrict__ outQ, bf16* __restrict__ outK, bf16* __restrict__ outVt,
    float* __restrict__ outF,
    int M, int N, int K)
{
  __shared__ bf16 sA[128 * 32];
  __shared__ bf16 sB[128 * 32];
  __shared__ bf16 sT[MODE == 0 ? 64 * 136 : 1];   // V^T bounce buffer
  const int tid  = threadIdx.x;
  const int wave = tid >> 6;
  const int lane = tid & 63;
  const int l15  = lane & 15;
  const int quad = lane >> 4;

  constexpr int NT = (MODE == 0) ? (QKVN / 128) : (DM / 128);
  const int lin = blockIdx.x;
  const int rem = lin % (NT * 8);
  const int m0 = ((lin / (NT * 8)) * 8 + (rem % 8)) * 128;
  const int n0 = (rem / 8) * 128;

  const int rowbase = (wave >> 1) * 64;
  const int colbase = (wave & 1) * 64;

  f32x4 acc[4][4] = {};

  const int sr = lane >> 2;
  const int sc = (lane & 3) * 8;

  for (int kt = 0; kt < K; kt += 32) {
#pragma unroll
    for (int p = 0; p < 4; ++p) {
      int chunk = p * 4 + wave;
      int r = (chunk & 7) * 16 + sr;
      if (chunk < 8) {
        async_ld16(A + (size_t)(m0 + r) * K + kt + sc, &sA[(chunk & 7) * 512]);
      } else {
        async_ld16(Bw + (size_t)(n0 + r) * K + kt + sc, &sB[(chunk & 7) * 512]);
      }
    }
    __syncthreads();

    bf16x8 af[4], bfr[4];
#pragma unroll
    for (int rt = 0; rt < 4; ++rt)
      af[rt] = *(const bf16x8*)&sA[(rowbase + rt * 16 + l15) * 32 + quad * 8];
#pragma unroll
    for (int ct = 0; ct < 4; ++ct)
      bfr[ct] = *(const bf16x8*)&sB[(colbase + ct * 16 + l15) * 32 + quad * 8];
#pragma unroll
    for (int rt = 0; rt < 4; ++rt)
#pragma unroll
      for (int ct = 0; ct < 4; ++ct)
        acc[rt][ct] = __builtin_amdgcn_mfma_f32_16x16x32_bf16(af[rt], bfr[ct], acc[rt][ct], 0, 0, 0);
    __syncthreads();
  }

  if (MODE == 0) {
    const int g = n0 / DM;                       // uniform per block (0=q,1=k,2=v)
    if (g < 2) {
      const float qscale = 0.125f * 1.4426950408889634f;  // fold /8 and log2(e) for exp2
#pragma unroll
      for (int ct = 0; ct < 4; ++ct) {
        int j = n0 + colbase + ct * 16 + l15;
        float bj = bias[j];
        int f = j % DM;
        int h = f >> 6, d = f & 63;
#pragma unroll
        for (int rt = 0; rt < 4; ++rt) {
          int mrow = m0 + rowbase + rt * 16 + quad * 4;
#pragma unroll
          for (int r = 0; r < 4; ++r) {
            float v = acc[rt][ct][r] + bj;
            int m = mrow + r;
            int b = m >> 12, n = m & 4095;
            int bh = b * NH + h;
            if (g == 0) outQ[((size_t)bh * SEQ + n) * DH + d] = (bf16)(v * qscale);
            else        outK[((size_t)bh * SEQ + n) * DH + d] = (bf16)v;
          }
        }
      }
    } else {
      // V block: bounce through LDS, store V^T coalesced along n
      const int f0 = n0 - 2 * DM;
      const int b = m0 >> 12, n0m = m0 & 4095;
#pragma unroll
      for (int p = 0; p < 2; ++p) {
        __syncthreads();
        if (colbase == p * 64) {
#pragma unroll
          for (int ct = 0; ct < 4; ++ct) {
            int jl = ct * 16 + l15;
            float bj = bias[n0 + p * 64 + jl];
#pragma unroll
            for (int rt = 0; rt < 4; ++rt) {
              int ml = rowbase + rt * 16 + quad * 4;
#pragma unroll
              for (int r = 0; r < 4; ++r)
                sT[jl * 136 + ml + r] = (bf16)(acc[rt][ct][r] + bj);
            }
          }
        }
        __syncthreads();
#pragma unroll
        for (int p2 = 0; p2 < 4; ++p2) {
          int slot = p2 * 256 + tid;
          int jr = slot >> 4, mc = (slot & 15) * 8;
          int fj = f0 + p * 64 + jr;
          int h = fj >> 6, d = fj & 63;
          *(bf16x8*)&outVt[((size_t)(b * NH + h) * DH + d) * SEQ + n0m + mc] =
              *(const bf16x8*)&sT[jr * 136 + mc];
        }
      }
    }
  } else {
#pragma unroll
    for (int ct = 0; ct < 4; ++ct) {
      int j = n0 + colbase + ct * 16 + l15;
      float bj = bias[j];
#pragma unroll
      for (int rt = 0; rt < 4; ++rt) {
        int mrow = m0 + rowbase + rt * 16 + quad * 4;
#pragma unroll
        for (int r = 0; r < 4; ++r)
          outF[(size_t)(mrow + r) * N + j] = acc[rt][ct][r] + bj;
      }
    }
  }
}

// ---------------------------------------------------------------- flash attention v14
// = R12 flash + block de-phase skew. R12 counters: MFMA-busy (60us) + VALU-busy
// (63us) ~= total (130us) -> pipes serialized. Hypothesis: co-resident waves
// (same wave-index, different blocks, identical barrier cadence) are PHASE-LOCKED
// in the ~520-cyc S->exp->PV cycle, so cross-wave MFMA/VALU overlap (m114) never
// happens. Fix: one-time entry skew of 0/128/256/384 cyc keyed by block index;
// block-internal barriers preserve the skew for the whole kernel. Zero registers,
// zero steady-state instructions.
__global__ __launch_bounds__(256) void flash_attn(
    const bf16* __restrict__ Q, const bf16* __restrict__ Kg,
    const bf16* __restrict__ Vt, bf16* __restrict__ Oout)
{
  __shared__ bf16 sK[2][64 * 64];    // [key][d], granule-swizzled
  __shared__ bf16 sV[2][64 * 64];    // [d][key], granule-swizzled

  // de-phase: quarter-period stagger by block index (s_sleep arg is imm, ~64 cyc/unit)
  {
    int ph = (blockIdx.x + blockIdx.y) & 3;
    if (ph == 1) __builtin_amdgcn_s_sleep(2);
    else if (ph == 2) __builtin_amdgcn_s_sleep(4);
    else if (ph == 3) __builtin_amdgcn_s_sleep(6);
  }

  const int tid  = threadIdx.x;
  const int wave = tid >> 6;
  const int lane = tid & 63;
  const int l31  = lane & 31;
  const int hi   = lane >> 5;
  const int bh = blockIdx.y;
  const int q0w = blockIdx.x * 128 + wave * 32;

  const bf16* Qb = Q  + (size_t)bh * SEQ * DH;
  const bf16* Kb = Kg + (size_t)bh * SEQ * DH;
  const bf16* Vb = Vt + (size_t)bh * DH * SEQ;

  const int srow = lane >> 3;
  const int spg  = lane & 7;

  bf16x8 qf[4];
#pragma unroll
  for (int dc = 0; dc < 4; ++dc)
    qf[dc] = *(const bf16x8*)&Qb[(size_t)(q0w + l31) * DH + dc * 16 + hi * 8];

  bf16x8 ones1;
#pragma unroll
  for (int j = 0; j < 8; ++j) ones1[j] = (bf16)1.0f;

  f32x16 o0 = {}, o1 = {}, o2 = {};
  f32x16 zc = {};

  const int keyk = (l31 & 7) ^ (((l31 >> 3) & 3) << 1);
  int kOff[4], vOff[4];
#pragma unroll
  for (int dc = 0; dc < 4; ++dc)
    kOff[dc] = l31 * 64 + (((dc * 2 + hi) ^ keyk) * 8);
#pragma unroll
  for (int k4 = 0; k4 < 4; ++k4)
    vOff[k4] = l31 * 64 + (((k4 * 2 + hi) ^ keyk) * 8);

  auto stage = [&](int kt, int buf) {
#pragma unroll
    for (int j = 0; j < 2; ++j) {
      int r0 = wave * 16 + j * 8;
      int row = r0 + srow;
      int lg = spg ^ (row & 7) ^ (((row >> 3) & 3) << 1);
      async_ld16(Kb + (size_t)(kt + row) * DH + lg * 8, &sK[buf][r0 * 64]);
      async_ld16(Vb + (size_t)row * SEQ + kt + lg * 8, &sV[buf][r0 * 64]);
    }
  };

  auto compute = [&](const bf16* sKp, const bf16* sVp) {
#pragma unroll
    for (int kb = 0; kb < 2; ++kb) {
      f32x16 s;
      {
        bf16x8 kf = *(const bf16x8*)&sKp[kOff[0] + kb * 2048];
        s = __builtin_amdgcn_mfma_f32_32x32x16_bf16(kf, qf[0], zc, 0, 0, 0);
      }
#pragma unroll
      for (int dc = 1; dc < 4; ++dc) {
        bf16x8 kf = *(const bf16x8*)&sKp[kOff[dc] + kb * 2048];
        s = __builtin_amdgcn_mfma_f32_32x32x16_bf16(kf, qf[dc], s, 0, 0, 0);
      }
#pragma unroll
      for (int kc = 0; kc < 2; ++kc) {
        int g0a = pexp2_pair(s[8 * kc + 0], s[8 * kc + 1]);
        int g0b = pexp2_pair(s[8 * kc + 2], s[8 * kc + 3]);
        int g1a = pexp2_pair(s[8 * kc + 4], s[8 * kc + 5]);
        int g1b = pexp2_pair(s[8 * kc + 6], s[8 * kc + 7]);
        lane32_swap(g0a, g1a);
        lane32_swap(g0b, g1b);
        union { int i[4]; bf16x8 v; } Af;
        Af.i[0] = g0a; Af.i[1] = g0b; Af.i[2] = g1a; Af.i[3] = g1b;
        bf16x8 vf0 = *(const bf16x8*)&sVp[vOff[kb * 2 + kc]];
        bf16x8 vf1 = *(const bf16x8*)&sVp[vOff[kb * 2 + kc] + 2048];
        o0 = __builtin_amdgcn_mfma_f32_32x32x16_bf16(Af.v, vf0, o0, 0, 0, 0);
        o1 = __builtin_amdgcn_mfma_f32_32x32x16_bf16(Af.v, vf1, o1, 0, 0, 0);
        o2 = __builtin_amdgcn_mfma_f32_32x32x16_bf16(Af.v, ones1, o2, 0, 0, 0);
      }
    }
  };

  stage(0, 0);
  __syncthreads();

  for (int kt = 0; kt < SEQ; kt += 128) {
    if (kt + 64 < SEQ) stage(kt + 64, 1);
    compute(sK[0], sV[0]);
    __syncthreads();
    if (kt + 128 < SEQ) stage(kt + 128, 0);
    compute(sK[1], sV[1]);
    __syncthreads();
  }

  const int bg = bh / NH, h = bh % NH;
#pragma unroll
  for (int i = 0; i < 16; ++i) {
    int ql = 8 * (i >> 2) + (i & 3) + 4 * hi;
    float inv = 1.0f / o2[i];
    size_t base = (size_t)(bg * SEQ + q0w + ql) * DM + h * DH;
    Oout[base + l31]      = (bf16)(o0[i] * inv);
    Oout[base + 32 + l31] = (bf16)(o1[i] * inv);
  }
}

// ---------------------------------------------------------------- launcher
extern "C" void kernel_launch(void* const* d_in, const int* in_sizes, int n_in,
                              void* d_out, int out_size, void* d_ws, size_t ws_size,
                              hipStream_t stream) {
  const float* x     = (const float*)d_in[0];
  const float* qkv_w = (const float*)d_in[1];
  const float* qkv_b = (const float*)d_in[2];
  const float* out_w = (const float*)d_in[3];
  const float* out_b = (const float*)d_in[4];
  float* out = (float*)d_out;

  char* w = (char*)d_ws;
  bf16* xb    = (bf16*)w; w += (size_t)MT * DM * 2;
  bf16* wqkv  = (bf16*)w; w += (size_t)QKVN * DM * 2;
  bf16* wout  = (bf16*)w; w += (size_t)DM * DM * 2;
  bf16* Qw    = (bf16*)w; w += (size_t)MT * DM * 2;        // [bh][n][d], scaled 0.125*log2e
  bf16* Kw    = (bf16*)w; w += (size_t)MT * DM * 2;        // [bh][n][d]
  bf16* Vtw   = (bf16*)w; w += (size_t)MT * DM * 2;        // [bh][d][n]
  bf16* attnV = (bf16*)w; w += (size_t)MT * DM * 2;        // [m][768]

  const int tot4 = NX4 + NW14 + NW24;
  cvt_all<<<dim3((tot4 + 255) / 256), 256, 0, stream>>>(x, qkv_w, out_w, xb, wqkv, wout);

  gemm_bt<0><<<dim3((QKVN / 128) * (MT / 128)), 256, 0, stream>>>(
      xb, wqkv, qkv_b, Qw, Kw, Vtw, nullptr, MT, QKVN, DM);

  flash_attn<<<dim3(SEQ / 128, 2 * NH), 256, 0, stream>>>(Qw, Kw, Vtw, attnV);

  gemm_bt<1><<<dim3((DM / 128) * (MT / 128)), 256, 0, stream>>>(
      attnV, wout, out_b, nullptr, nullptr, nullptr, out, MT, DM, DM);
}

// Round 15
// 263.813 us; speedup vs baseline: 1.1419x; 1.0672x over previous
//
#include <hip/hip_runtime.h>
#include <cstdint>

#define SEQ 4096
#define NH 12
#define DH 64
#define DM 768
#define MT 8192      // B*SEQ
#define QKVN 2304    // 3*DM

typedef __bf16 bf16;
typedef __attribute__((ext_vector_type(8))) __bf16 bf16x8;
typedef __attribute__((ext_vector_type(4))) __bf16 bf16x4;
typedef __attribute__((ext_vector_type(2))) __bf16 bf16x2;
typedef __attribute__((ext_vector_type(4))) float f32x4;
typedef __attribute__((ext_vector_type(16))) float f32x16;
typedef __attribute__((ext_vector_type(2))) int int2v;

// async global->LDS, 16B per lane. LDS dest is wave-uniform base + lane*16.
__device__ __forceinline__ void async_ld16(const void* g, void* lds) {
  __builtin_amdgcn_global_load_lds(
      (__attribute__((address_space(1))) void*)(void*)g,
      (__attribute__((address_space(3))) void*)lds, 16, 0, 0);
}

// Schraudolph-style exp2 emitting BF16 BITS directly, two elements packed.
// bf16(2^s) bits ~= (int)(s*128 + 16251.5); +-3.5% rel, softmax-ratio cancels
// the common mode. Integer/VALU only — never touches the trans pipe.
__device__ __forceinline__ int pexp2_pair(float s0, float s1) {
  int j0 = (int)__builtin_fmaf(s0, 128.0f, 16251.5f);
  int j1 = (int)__builtin_fmaf(s1, 128.0f, 16251.5f);
  return j0 | (j1 << 16);
}

// (a,b) -> a' = {a.lo32, b.lo32}, b' = {a.hi32, b.hi32}
__device__ __forceinline__ void lane32_swap(int& a, int& b) {
#if __has_builtin(__builtin_amdgcn_permlane32_swap)
  int2v r = __builtin_amdgcn_permlane32_swap(a, b, false, false);
  a = r.x; b = r.y;
#else
  int hi = (threadIdx.x & 63) >> 5;
  int ra = __shfl_xor(a, 32, 64), rb = __shfl_xor(b, 32, 64);
  int na = hi ? rb : a;
  int nb = hi ? b : ra;
  a = na; b = nb;
#endif
}

// ---------------------------------------------------------------- converts (merged)
#define NX4  (MT * DM / 4)
#define NW14 (QKVN * DM / 4)
#define NW24 (DM * DM / 4)
__global__ void cvt_all(const float* __restrict__ x, const float* __restrict__ w1,
                        const float* __restrict__ w2, bf16* __restrict__ xb,
                        bf16* __restrict__ wb1, bf16* __restrict__ wb2) {
  int i = blockIdx.x * blockDim.x + threadIdx.x;
  const float* src; bf16* dst; int j;
  if (i < NX4) { src = x; dst = xb; j = i; }
  else if (i < NX4 + NW14) { src = w1; dst = wb1; j = i - NX4; }
  else if (i < NX4 + NW14 + NW24) { src = w2; dst = wb2; j = i - NX4 - NW14; }
  else return;
  f32x4 v = ((const f32x4*)src)[j];
  bf16x4 o;
  o.x = (bf16)v.x; o.y = (bf16)v.y; o.z = (bf16)v.z; o.w = (bf16)v.w;
  ((bf16x4*)dst)[j] = o;
}

// ---------------------------------------------------------------- GEMM (B^T)
// C[M,N] = A[M,K] @ Bw[N,K]^T. 128x128 tile, BK=64 (R15: halves barrier drains,
// 24->12 iters at K=768; 32 MFMAs per staging round). 4 waves, 64x64/wave.
// 128B LDS rows would 16-way-conflict fragment b128 reads, so the 16B granule is
// XOR-swizzled on the GLOBAL side (pg = (lane&7)^(lane>>3)); fragment reads use
// g = G ^ (row&7) -> 8 accesses/bank per b128 (hardware minimum, conflict-free).
// V^T bounce buffer sT ALIASES sA/sB (only live after the K-loop's last barrier)
// so MODE-0 LDS stays 32 KB. 1-D grid, grouped swizzle (R10-verified).
// MODE 0: QKV epilogue -> +bias, Q(*0.125*log2e)/K as [bh][n][d]; V^T -> [bh][d][n]
// MODE 1: out-proj epilogue -> +bias, fp32 row-major [M,N]
template<int MODE>
__global__ __launch_bounds__(256) void gemm_bt(
    const bf16* __restrict__ A, const bf16* __restrict__ Bw,
    const float* __restrict__ bias,
    bf16* __restrict__ outQ, bf16* __restrict__ outK, bf16* __restrict__ outVt,
    float* __restrict__ outF,
    int M, int N, int K)
{
  __shared__ bf16 smem[2 * 128 * 64];   // sA | sB ; sT aliases the front 17.4 KB
  bf16* sA = smem;
  bf16* sB = smem + 128 * 64;
  bf16* sT = smem;                      // reused only after the final K-loop barrier

  const int tid  = threadIdx.x;
  const int wave = tid >> 6;
  const int lane = tid & 63;
  const int l15  = lane & 15;
  const int quad = lane >> 4;

  constexpr int NT = (MODE == 0) ? (QKVN / 128) : (DM / 128);
  const int lin = blockIdx.x;
  const int rem = lin % (NT * 8);
  const int m0 = ((lin / (NT * 8)) * 8 + (rem % 8)) * 128;
  const int n0 = (rem / 8) * 128;

  const int rowbase = (wave >> 1) * 64;
  const int colbase = (wave & 1) * 64;

  f32x4 acc[4][4] = {};

  const int srow = lane >> 3;            // row within 8-row chunk
  const int spg  = (lane & 7) ^ srow;    // swizzled 16B granule within 128B row
  const int xk   = l15 & 7;              // fragment-read swizzle key

  for (int kt = 0; kt < K; kt += 64) {
    // 32 chunks of 1KB (8 rows x 64 bf16): 16 for A, 16 for B; chunk = p*4+wave
#pragma unroll
    for (int p = 0; p < 8; ++p) {
      int chunk = p * 4 + wave;
      if (chunk < 16) {
        int row = chunk * 8 + srow;
        async_ld16(A + (size_t)(m0 + row) * K + kt + spg * 8, &sA[chunk * 512]);
      } else {
        int row = (chunk - 16) * 8 + srow;
        async_ld16(Bw + (size_t)(n0 + row) * K + kt + spg * 8, &sB[(chunk - 16) * 512]);
      }
    }
    __syncthreads();

#pragma unroll
    for (int ks = 0; ks < 2; ++ks) {
      bf16x8 af[4], bfr[4];
#pragma unroll
      for (int rt = 0; rt < 4; ++rt)
        af[rt] = *(const bf16x8*)&sA[(rowbase + rt * 16 + l15) * 64 +
                                     (((ks * 4 + quad) ^ xk) * 8)];
#pragma unroll
      for (int ct = 0; ct < 4; ++ct)
        bfr[ct] = *(const bf16x8*)&sB[(colbase + ct * 16 + l15) * 64 +
                                      (((ks * 4 + quad) ^ xk) * 8)];
#pragma unroll
      for (int rt = 0; rt < 4; ++rt)
#pragma unroll
        for (int ct = 0; ct < 4; ++ct)
          acc[rt][ct] = __builtin_amdgcn_mfma_f32_16x16x32_bf16(af[rt], bfr[ct], acc[rt][ct], 0, 0, 0);
    }
    __syncthreads();
  }

  if (MODE == 0) {
    const int g = n0 / DM;                       // uniform per block (0=q,1=k,2=v)
    if (g < 2) {
      const float qscale = 0.125f * 1.4426950408889634f;  // fold /8 and log2(e)
#pragma unroll
      for (int ct = 0; ct < 4; ++ct) {
        int j = n0 + colbase + ct * 16 + l15;
        float bj = bias[j];
        int f = j % DM;
        int h = f >> 6, d = f & 63;
#pragma unroll
        for (int rt = 0; rt < 4; ++rt) {
          int mrow = m0 + rowbase + rt * 16 + quad * 4;
#pragma unroll
          for (int r = 0; r < 4; ++r) {
            float v = acc[rt][ct][r] + bj;
            int m = mrow + r;
            int b = m >> 12, n = m & 4095;
            int bh = b * NH + h;
            if (g == 0) outQ[((size_t)bh * SEQ + n) * DH + d] = (bf16)(v * qscale);
            else        outK[((size_t)bh * SEQ + n) * DH + d] = (bf16)v;
          }
        }
      }
    } else {
      // V block: bounce through LDS (sT aliases sA/sB — safe after barrier),
      // store V^T coalesced along n
      const int f0 = n0 - 2 * DM;
      const int b = m0 >> 12, n0m = m0 & 4095;
#pragma unroll
      for (int p = 0; p < 2; ++p) {
        __syncthreads();
        if (colbase == p * 64) {
#pragma unroll
          for (int ct = 0; ct < 4; ++ct) {
            int jl = ct * 16 + l15;
            float bj = bias[n0 + p * 64 + jl];
#pragma unroll
            for (int rt = 0; rt < 4; ++rt) {
              int ml = rowbase + rt * 16 + quad * 4;
#pragma unroll
              for (int r = 0; r < 4; ++r)
                sT[jl * 136 + ml + r] = (bf16)(acc[rt][ct][r] + bj);
            }
          }
        }
        __syncthreads();
#pragma unroll
        for (int p2 = 0; p2 < 4; ++p2) {
          int slot = p2 * 256 + tid;
          int jr = slot >> 4, mc = (slot & 15) * 8;
          int fj = f0 + p * 64 + jr;
          int h = fj >> 6, d = fj & 63;
          *(bf16x8*)&outVt[((size_t)(b * NH + h) * DH + d) * SEQ + n0m + mc] =
              *(const bf16x8*)&sT[jr * 136 + mc];
        }
      }
    }
  } else {
#pragma unroll
    for (int ct = 0; ct < 4; ++ct) {
      int j = n0 + colbase + ct * 16 + l15;
      float bj = bias[j];
#pragma unroll
      for (int rt = 0; rt < 4; ++rt) {
        int mrow = m0 + rowbase + rt * 16 + quad * 4;
#pragma unroll
        for (int r = 0; r < 4; ++r)
          outF[(size_t)(mrow + r) * N + j] = acc[rt][ct][r] + bj;
      }
    }
  }
}

// ---------------------------------------------------------------- flash attention v14
// R12 flash + de-phase sleep (R14: neutral-to-slightly-positive, 125.4 us).
// Structurally pinned ~125 us: MFMA-busy + VALU-busy ~= total at the register
// cliff (84 arch + 64 acc VGPR -> ~3 waves/SIMD); R5/R10/R11/R14 all failed to
// buy more overlap. Schraudolph bf16-bit exp (R9), ones-column MFMA row-sums,
// async dbuf global_load_lds staging, global-side XOR granule swizzle.
__global__ __launch_bounds__(256) void flash_attn(
    const bf16* __restrict__ Q, const bf16* __restrict__ Kg,
    const bf16* __restrict__ Vt, bf16* __restrict__ Oout)
{
  __shared__ bf16 sK[2][64 * 64];    // [key][d], granule-swizzled
  __shared__ bf16 sV[2][64 * 64];    // [d][key], granule-swizzled

  {
    int ph = (blockIdx.x + blockIdx.y) & 3;
    if (ph == 1) __builtin_amdgcn_s_sleep(2);
    else if (ph == 2) __builtin_amdgcn_s_sleep(4);
    else if (ph == 3) __builtin_amdgcn_s_sleep(6);
  }

  const int tid  = threadIdx.x;
  const int wave = tid >> 6;
  const int lane = tid & 63;
  const int l31  = lane & 31;
  const int hi   = lane >> 5;
  const int bh = blockIdx.y;
  const int q0w = blockIdx.x * 128 + wave * 32;

  const bf16* Qb = Q  + (size_t)bh * SEQ * DH;
  const bf16* Kb = Kg + (size_t)bh * SEQ * DH;
  const bf16* Vb = Vt + (size_t)bh * DH * SEQ;

  const int srow = lane >> 3;
  const int spg  = lane & 7;

  bf16x8 qf[4];
#pragma unroll
  for (int dc = 0; dc < 4; ++dc)
    qf[dc] = *(const bf16x8*)&Qb[(size_t)(q0w + l31) * DH + dc * 16 + hi * 8];

  bf16x8 ones1;
#pragma unroll
  for (int j = 0; j < 8; ++j) ones1[j] = (bf16)1.0f;

  f32x16 o0 = {}, o1 = {}, o2 = {};
  f32x16 zc = {};

  const int keyk = (l31 & 7) ^ (((l31 >> 3) & 3) << 1);
  int kOff[4], vOff[4];
#pragma unroll
  for (int dc = 0; dc < 4; ++dc)
    kOff[dc] = l31 * 64 + (((dc * 2 + hi) ^ keyk) * 8);
#pragma unroll
  for (int k4 = 0; k4 < 4; ++k4)
    vOff[k4] = l31 * 64 + (((k4 * 2 + hi) ^ keyk) * 8);

  auto stage = [&](int kt, int buf) {
#pragma unroll
    for (int j = 0; j < 2; ++j) {
      int r0 = wave * 16 + j * 8;
      int row = r0 + srow;
      int lg = spg ^ (row & 7) ^ (((row >> 3) & 3) << 1);
      async_ld16(Kb + (size_t)(kt + row) * DH + lg * 8, &sK[buf][r0 * 64]);
      async_ld16(Vb + (size_t)row * SEQ + kt + lg * 8, &sV[buf][r0 * 64]);
    }
  };

  auto compute = [&](const bf16* sKp, const bf16* sVp) {
#pragma unroll
    for (int kb = 0; kb < 2; ++kb) {
      f32x16 s;
      {
        bf16x8 kf = *(const bf16x8*)&sKp[kOff[0] + kb * 2048];
        s = __builtin_amdgcn_mfma_f32_32x32x16_bf16(kf, qf[0], zc, 0, 0, 0);
      }
#pragma unroll
      for (int dc = 1; dc < 4; ++dc) {
        bf16x8 kf = *(const bf16x8*)&sKp[kOff[dc] + kb * 2048];
        s = __builtin_amdgcn_mfma_f32_32x32x16_bf16(kf, qf[dc], s, 0, 0, 0);
      }
#pragma unroll
      for (int kc = 0; kc < 2; ++kc) {
        int g0a = pexp2_pair(s[8 * kc + 0], s[8 * kc + 1]);
        int g0b = pexp2_pair(s[8 * kc + 2], s[8 * kc + 3]);
        int g1a = pexp2_pair(s[8 * kc + 4], s[8 * kc + 5]);
        int g1b = pexp2_pair(s[8 * kc + 6], s[8 * kc + 7]);
        lane32_swap(g0a, g1a);
        lane32_swap(g0b, g1b);
        union { int i[4]; bf16x8 v; } Af;
        Af.i[0] = g0a; Af.i[1] = g0b; Af.i[2] = g1a; Af.i[3] = g1b;
        bf16x8 vf0 = *(const bf16x8*)&sVp[vOff[kb * 2 + kc]];
        bf16x8 vf1 = *(const bf16x8*)&sVp[vOff[kb * 2 + kc] + 2048];
        o0 = __builtin_amdgcn_mfma_f32_32x32x16_bf16(Af.v, vf0, o0, 0, 0, 0);
        o1 = __builtin_amdgcn_mfma_f32_32x32x16_bf16(Af.v, vf1, o1, 0, 0, 0);
        o2 = __builtin_amdgcn_mfma_f32_32x32x16_bf16(Af.v, ones1, o2, 0, 0, 0);
      }
    }
  };

  stage(0, 0);
  __syncthreads();

  for (int kt = 0; kt < SEQ; kt += 128) {
    if (kt + 64 < SEQ) stage(kt + 64, 1);
    compute(sK[0], sV[0]);
    __syncthreads();
    if (kt + 128 < SEQ) stage(kt + 128, 0);
    compute(sK[1], sV[1]);
    __syncthreads();
  }

  const int bg = bh / NH, h = bh % NH;
#pragma unroll
  for (int i = 0; i < 16; ++i) {
    int ql = 8 * (i >> 2) + (i & 3) + 4 * hi;
    float inv = 1.0f / o2[i];
    size_t base = (size_t)(bg * SEQ + q0w + ql) * DM + h * DH;
    Oout[base + l31]      = (bf16)(o0[i] * inv);
    Oout[base + 32 + l31] = (bf16)(o1[i] * inv);
  }
}

// ---------------------------------------------------------------- launcher
extern "C" void kernel_launch(void* const* d_in, const int* in_sizes, int n_in,
                              void* d_out, int out_size, void* d_ws, size_t ws_size,
                              hipStream_t stream) {
  const float* x     = (const float*)d_in[0];
  const float* qkv_w = (const float*)d_in[1];
  const float* qkv_b = (const float*)d_in[2];
  const float* out_w = (const float*)d_in[3];
  const float* out_b = (const float*)d_in[4];
  float* out = (float*)d_out;

  char* w = (char*)d_ws;
  bf16* xb    = (bf16*)w; w += (size_t)MT * DM * 2;
  bf16* wqkv  = (bf16*)w; w += (size_t)QKVN * DM * 2;
  bf16* wout  = (bf16*)w; w += (size_t)DM * DM * 2;
  bf16* Qw    = (bf16*)w; w += (size_t)MT * DM * 2;        // [bh][n][d], scaled 0.125*log2e
  bf16* Kw    = (bf16*)w; w += (size_t)MT * DM * 2;        // [bh][n][d]
  bf16* Vtw   = (bf16*)w; w += (size_t)MT * DM * 2;        // [bh][d][n]
  bf16* attnV = (bf16*)w; w += (size_t)MT * DM * 2;        // [m][768]

  const int tot4 = NX4 + NW14 + NW24;
  cvt_all<<<dim3((tot4 + 255) / 256), 256, 0, stream>>>(x, qkv_w, out_w, xb, wqkv, wout);

  gemm_bt<0><<<dim3((QKVN / 128) * (MT / 128)), 256, 0, stream>>>(
      xb, wqkv, qkv_b, Qw, Kw, Vtw, nullptr, MT, QKVN, DM);

  flash_attn<<<dim3(SEQ / 128, 2 * NH), 256, 0, stream>>>(Qw, Kw, Vtw, attnV);

  gemm_bt<1><<<dim3((DM / 128) * (MT / 128)), 256, 0, stream>>>(
      attnV, wout, out_b, nullptr, nullptr, nullptr, out, MT, DM, DM);
}